// Round 4
// baseline (449.158 us; speedup 1.0000x reference)
//
#include <hip/hip_runtime.h>
#include <hip/hip_bf16.h>
#include <stdint.h>

// Int8Linear: per-row symmetric int8 quant (w per-output-channel, x per-token),
// int8 GEMM (exact int32 accum via MFMA i8), fused dequant + bf16 bias epilogue.
// M=8192, K=4096, N=4096 for this problem instance.
//
// R4 changes vs R3:
//  - K-loop restructured: register-staged software pipeline. After the single
//    per-iter barrier, issue global_load_dwordx4 for tile k+1 into VGPRs (no
//    wait), compute tile k from LDS, then ds_write regs into the other LDS
//    buffer (compiler places vmcnt wait there, NOT at the barrier). This
//    removes the per-iter barrier-drain of staging (R3: ~60% stall).
//  - 1 barrier/iter (was 2), double-buffered LDS (32 KB).
// Kept from R3: 32x32x32 i8 MFMA, chunk swizzle layout, fused quant.

using i32x4  = __attribute__((ext_vector_type(4))) int;
using i32x16 = __attribute__((ext_vector_type(16))) int;

#define TILE 128
#define BK 64   // int8 elements of K per LDS stage

// ---------------------------------------------------------------------------
// Fused per-row quantization for both W [N,K] and X [M,K]; block b < nw does
// weight row b, else x row b-nw. 256 threads, K=4096.
// scale = max(absmax/127, 1e-12); q = clip(rint(v/scale), -128, 127).
// ---------------------------------------------------------------------------
__global__ __launch_bounds__(256) void quant_rows_fused(
    const float* __restrict__ w_in, const float* __restrict__ x_in,
    int8_t* __restrict__ w_q, int8_t* __restrict__ x_q,
    float* __restrict__ w_s, float* __restrict__ x_s,
    int nw, int K)
{
    const int b   = blockIdx.x;
    const bool is_w = (b < nw);
    const int row = is_w ? b : (b - nw);
    const float* r = (is_w ? w_in : x_in) + (size_t)row * K;
    int8_t* qout   = (is_w ? w_q : x_q) + (size_t)row * K;
    float* scales  = is_w ? w_s : x_s;

    const int tid = threadIdx.x;

    float4 v[4];
#pragma unroll
    for (int j = 0; j < 4; ++j)
        v[j] = *(const float4*)(r + j * 1024 + tid * 4);   // coalesced

    float amax = 0.f;
#pragma unroll
    for (int j = 0; j < 4; ++j) {
        amax = fmaxf(amax, fabsf(v[j].x));
        amax = fmaxf(amax, fabsf(v[j].y));
        amax = fmaxf(amax, fabsf(v[j].z));
        amax = fmaxf(amax, fabsf(v[j].w));
    }

#pragma unroll
    for (int off = 32; off >= 1; off >>= 1)
        amax = fmaxf(amax, __shfl_xor(amax, off));

    __shared__ float red[4];
    const int wave = tid >> 6;
    if ((tid & 63) == 0) red[wave] = amax;
    __syncthreads();
    amax = fmaxf(fmaxf(red[0], red[1]), fmaxf(red[2], red[3]));

    const float scale = fmaxf(amax / 127.0f, 1e-12f);
    if (tid == 0) scales[row] = scale;

#pragma unroll
    for (int j = 0; j < 4; ++j) {
        float q0 = fminf(fmaxf(rintf(v[j].x / scale), -128.f), 127.f);
        float q1 = fminf(fmaxf(rintf(v[j].y / scale), -128.f), 127.f);
        float q2 = fminf(fmaxf(rintf(v[j].z / scale), -128.f), 127.f);
        float q3 = fminf(fmaxf(rintf(v[j].w / scale), -128.f), 127.f);
        union { signed char c[4]; int i; } u;
        u.c[0] = (signed char)(int)q0;
        u.c[1] = (signed char)(int)q1;
        u.c[2] = (signed char)(int)q2;
        u.c[3] = (signed char)(int)q3;
        *(int*)(qout + j * 1024 + tid * 4) = u.i;
    }
}

// ---------------------------------------------------------------------------
// int8 GEMM: C[M][N] = A[M][K] . B[N][K]^T, int32 accum, fused dequant.
// 128x128 tile, BK=64, 4 waves (2x2, 64x64 each), 32x32x32 i8 MFMA,
// 2x2 MFMA tiles per wave, register-staged double-buffered pipeline.
//
// LDS layout per buffer: A tile [128 rows][64 B] then B tile, with chunk
// swizzle: logical 16B chunk c of row r stored at phys chunk (c+(r>>1))&3.
// Staging: thread t loads logical chunk (t&3) of rows (t>>2) and (t>>2)+64
// (phys chunk identical for both since +64 rows shifts (r>>1) by 32 = 0 mod 4).
//
// 32x32x32 i8 layouts:
//   A: m = lane&31, k = (lane>>5)*16 + j   (16 i8 per lane = i32x4)
//   C/D: col = lane&31, row = (reg&3) + 8*(reg>>2) + 4*(lane>>5)  [m74/m101]
// ---------------------------------------------------------------------------
__global__ __launch_bounds__(256) void gemm_i8_kernel(
    const int8_t* __restrict__ A,   // [M][K] x_i8
    const int8_t* __restrict__ B,   // [N][K] w_i8
    const float*  __restrict__ xs,  // [M] x scales
    const float*  __restrict__ ws,  // [N] w scales
    const float*  __restrict__ bias,// [N] fp32 bias
    float*        __restrict__ out, // [M][N] fp32
    int M, int N, int K)
{
    __shared__ __align__(16) int8_t sAB[2][2 * TILE * BK];  // 2 bufs x (A 8K + B 8K)

    const int tid   = threadIdx.x;
    const int wave  = tid >> 6;
    const int lane  = tid & 63;
    const int l31   = lane & 31;
    const int lhalf = lane >> 5;       // 0/1

    const int bm = blockIdx.y * TILE;
    const int bn = blockIdx.x * TILE;
    const int wm = (wave >> 1) * 64;
    const int wn = (wave & 1) * 64;

    i32x16 acc[2][2];
#pragma unroll
    for (int i = 0; i < 2; ++i)
#pragma unroll
        for (int j = 0; j < 2; ++j)
#pragma unroll
            for (int r = 0; r < 16; ++r) acc[i][j][r] = 0;

    // ---- staging assignment: thread t -> rows (t>>2, t>>2+64), logical chunk t&3
    const int srow   = tid >> 2;         // 0..63
    const int schunk = tid & 3;
    const int wchunk = ((schunk + ((srow >> 1) & 3)) & 3) * 16;  // phys chunk byte off

    const int8_t* ag0 = A + (size_t)(bm + srow) * K + schunk * 16;
    const int8_t* ag1 = A + (size_t)(bm + 64 + srow) * K + schunk * 16;
    const int8_t* bg0 = B + (size_t)(bn + srow) * K + schunk * 16;
    const int8_t* bg1 = B + (size_t)(bn + 64 + srow) * K + schunk * 16;

    const int wA0 = srow * 64 + wchunk;          // within-buffer byte offsets
    const int wA1 = (srow + 64) * 64 + wchunk;
    const int wB0 = 8192 + srow * 64 + wchunk;
    const int wB1 = 8192 + (srow + 64) * 64 + wchunk;

    // fragment-read physical chunks: logical chunk = lhalf + khalf*2,
    // phys = (logical + (r>>1)) & 3; wm/it*32 contribute 0 mod 4 after >>1.
    const int pc0 = ((lhalf + 0 + (l31 >> 1)) & 3) * 16;   // khalf=0
    const int pc1 = ((lhalf + 2 + (l31 >> 1)) & 3) * 16;   // khalf=1

    // ---- prologue: stage tile 0 into buffer 0
    {
        i32x4 ra0 = *(const i32x4*)(ag0);
        i32x4 ra1 = *(const i32x4*)(ag1);
        i32x4 rb0 = *(const i32x4*)(bg0);
        i32x4 rb1 = *(const i32x4*)(bg1);
        int8_t* wb = sAB[0];
        *(i32x4*)(wb + wA0) = ra0;
        *(i32x4*)(wb + wA1) = ra1;
        *(i32x4*)(wb + wB0) = rb0;
        *(i32x4*)(wb + wB1) = rb1;
    }

    int buf = 0;
    for (int k0 = 0; k0 < K; k0 += BK, buf ^= 1) {
        // barrier: ds_writes of prev iter visible; reads of other buf done.
        // No vmem pending here (prev iter's loads consumed by its ds_writes)
        // -> the implicit vmcnt(0) drain is cheap.
        __syncthreads();

        // prefetch tile k+1 into registers (no wait until ds_write below)
        const int kn = (k0 + BK < K) ? (k0 + BK) : 0;   // last iter: dummy reload
        i32x4 ra0 = *(const i32x4*)(ag0 + kn);
        i32x4 ra1 = *(const i32x4*)(ag1 + kn);
        i32x4 rb0 = *(const i32x4*)(bg0 + kn);
        i32x4 rb1 = *(const i32x4*)(bg1 + kn);

        // compute tile k from sAB[buf] (overlaps the global loads above)
        const int8_t* rb = sAB[buf];
        i32x4 af[2][2], bfr[2][2];   // [tile][khalf]
#pragma unroll
        for (int it = 0; it < 2; ++it) {
            const int arow = (wm + it * 32 + l31) * 64;
            af[it][0] = *(const i32x4*)(rb + arow + pc0);
            af[it][1] = *(const i32x4*)(rb + arow + pc1);
        }
#pragma unroll
        for (int jt = 0; jt < 2; ++jt) {
            const int brow = 8192 + (wn + jt * 32 + l31) * 64;
            bfr[jt][0] = *(const i32x4*)(rb + brow + pc0);
            bfr[jt][1] = *(const i32x4*)(rb + brow + pc1);
        }

#pragma unroll
        for (int kh = 0; kh < 2; ++kh)
#pragma unroll
            for (int it = 0; it < 2; ++it)
#pragma unroll
                for (int jt = 0; jt < 2; ++jt)
                    acc[it][jt] = __builtin_amdgcn_mfma_i32_32x32x32_i8(
                        af[it][kh], bfr[jt][kh], acc[it][jt], 0, 0, 0);

        // stage tile k+1 into the other buffer (compiler waits vmcnt here)
        int8_t* wb = sAB[buf ^ 1];
        *(i32x4*)(wb + wA0) = ra0;
        *(i32x4*)(wb + wA1) = ra1;
        *(i32x4*)(wb + wB0) = rb0;
        *(i32x4*)(wb + wB1) = rb1;
    }

    // Epilogue: out = fp32( bf16( bf16(acc*xs*ws) + bf16(bias) ) )
    // C/D: col = lane&31, row = (reg&3) + 8*(reg>>2) + 4*(lane>>5)
#pragma unroll
    for (int jt = 0; jt < 2; ++jt) {
        const int col = bn + wn + jt * 32 + l31;
        const float wsv = ws[col];
        const float bsv = __bfloat162float(__float2bfloat16(bias[col]));
#pragma unroll
        for (int it = 0; it < 2; ++it) {
            const int rowbase = bm + wm + it * 32 + 4 * lhalf;
#pragma unroll
            for (int r = 0; r < 16; ++r) {
                const int row = rowbase + (r & 3) + 8 * (r >> 2);
                const float v = (float)acc[it][jt][r] * xs[row] * wsv;
                const float vb = __bfloat162float(__float2bfloat16(v));
                const float res = __bfloat162float(__float2bfloat16(vb + bsv));
                out[(size_t)row * N + col] = res;
            }
        }
    }
}

// ---------------------------------------------------------------------------
extern "C" void kernel_launch(void* const* d_in, const int* in_sizes, int n_in,
                              void* d_out, int out_size, void* d_ws, size_t ws_size,
                              hipStream_t stream)
{
    const float* x    = (const float*)d_in[0];   // [B,S,K] fp32
    const float* wfp  = (const float*)d_in[1];   // [N,K] fp32
    const float* bias = (const float*)d_in[2];   // [N] fp32
    float* out = (float*)d_out;                  // [M,N] fp32

    const int N = in_sizes[2];
    const int K = in_sizes[1] / N;
    const int M = in_sizes[0] / K;

    // workspace layout: w_i8[N*K] | x_i8[M*K] | w_scales[N] | x_scales[M]
    int8_t* w_i8 = (int8_t*)d_ws;
    int8_t* x_i8 = w_i8 + (size_t)N * K;
    float* w_scales = (float*)(x_i8 + (size_t)M * K);
    float* x_scales = w_scales + N;

    quant_rows_fused<<<N + M, 256, 0, stream>>>(wfp, x, w_i8, x_i8,
                                                w_scales, x_scales, N, K);

    dim3 grid(N / TILE, M / TILE);
    gemm_i8_kernel<<<grid, 256, 0, stream>>>(x_i8, w_i8, x_scales, w_scales,
                                             bias, out, M, N, K);
}